// Round 7
// baseline (179.148 us; speedup 1.0000x reference)
//
#include <hip/hip_runtime.h>
#include <math.h>

#define NT 512   // threads per block; 512 blocks (one per channel h)

// Packed f32 pair: LLVM lowers arithmetic on this to v_pk_*_f32 (VOP3P) on gfx950.
typedef float v2 __attribute__((ext_vector_type(2)));

__device__ __forceinline__ v2 vrot(v2 a){ return (v2){-a.y, a.x}; }            // i*a
__device__ __forceinline__ v2 vconj(v2 a){ return (v2){a.x, -a.y}; }
__device__ __forceinline__ v2 vcmul(v2 a, v2 b){ return a.x*b + a.y*vrot(b); } // complex mul: 2 pk_fma
__device__ __forceinline__ v2 vfma1(float s, v2 v, v2 acc){                    // acc + s*v: 1 pk_fma
    return (v2){ __builtin_fmaf(s, v.x, acc.x), __builtin_fmaf(s, v.y, acc.y) };
}

// XOR bank swizzle: float2 elements -> bank = (2e)%32 depends on e mod 16.
__device__ __forceinline__ int SW(int e){ return e ^ (((e>>5) ^ (e>>9)) & 15); }

// base-4 digit reversal of a 12-bit index (P4 output ordering, as in R3)
__device__ __forceinline__ int d4r6(int x){
    int r = (int)(__builtin_bitreverse32((unsigned)x) >> 20);
    return ((r & 0x555) << 1) | ((r >> 1) & 0x555);
}
// base-8 digit reversal of a 12-bit index (P2/P6 radix-8 input ordering)
__device__ __forceinline__ int d8r4(int x){
    return ((x&7)<<9) | (((x>>3)&7)<<6) | (((x>>6)&7)<<3) | ((x>>9)&7);
}

// ---- 8-point DFT, inverse sign (sigma=+1), unnormalized. y_m = sum_k t_k w^{mk}, w=e^{i pi/4}
__device__ __forceinline__ void dft8_inv(v2 t[8], v2 y[8]) {
    const float RH = 0.70710678f;
    v2 p  = t[0]+t[4], m  = t[0]-t[4], q  = t[2]+t[6], r  = t[2]-t[6];
    v2 rr = vrot(r);
    v2 E0 = p+q, E2 = p-q, E1 = m+rr, E3 = m-rr;
    v2 p2 = t[1]+t[5], m2 = t[1]-t[5], q2 = t[3]+t[7], r2 = t[3]-t[7];
    v2 rr2 = vrot(r2);
    v2 O0 = p2+q2, O2 = p2-q2, O1 = m2+rr2, O3 = m2-rr2;
    v2 W1O = RH*(O1 + vrot(O1));        // w^1 * O1
    v2 W2O = vrot(O2);                  // w^2 = i
    v2 W3O = vrot(RH*(O3 + vrot(O3)));  // w^3 = i*w
    y[0] = E0 + O0;  y[4] = E0 - O0;
    y[1] = E1 + W1O; y[5] = E1 - W1O;
    y[2] = E2 + W2O; y[6] = E2 - W2O;
    y[3] = E3 + W3O; y[7] = E3 - W3O;
}

// ---- radix-8 DIT pass, inverse (sigma=+1), in-place. One butterfly per thread.
// Q in {1,8,64,512}; input base-8 digit-reversed, output natural after Q=512.
template<int Q, bool TW>
__device__ __forceinline__ void r8_dit_inv(v2* buf, int tid) {
    int j = tid & (Q-1);
    int base = 8*tid - 7*j;
    v2 t[8];
    #pragma unroll
    for (int k = 0; k < 8; ++k) t[k] = buf[SW(base + k*Q)];
    if (TW) {
        const float fm = 6.2831853072f / (float)(8*Q);
        float sb, cb; __sincosf(fm*(float)j, &sb, &cb);
        v2 W1 = (v2){cb, sb};
        v2 W2 = vcmul(W1,W1), W3 = vcmul(W1,W2), W4 = vcmul(W2,W2),
           W5 = vcmul(W2,W3), W6 = vcmul(W3,W3), W7 = vcmul(W3,W4);
        t[1]=vcmul(t[1],W1); t[2]=vcmul(t[2],W2); t[3]=vcmul(t[3],W3);
        t[4]=vcmul(t[4],W4); t[5]=vcmul(t[5],W5); t[6]=vcmul(t[6],W6);
        t[7]=vcmul(t[7],W7);
    }
    v2 y[8];
    dft8_inv(t, y);
    #pragma unroll
    for (int m = 0; m < 8; ++m) buf[SW(base + m*Q)] = y[m];
    __syncthreads();
}

// ---- radix-4 DIF butterfly core (sigma=-1), twiddled outputs (V1,V2,V3), in regs.
__device__ __forceinline__ void r4dif(v2& a0, v2& a1, v2& a2, v2& a3, v2 V1, v2 V2, v2 V3){
    v2 E0 = a0+a2, E1 = a1+a3, O0 = a0-a2, O1 = a1-a3, rr = vrot(O1);
    a0 = E0+E1;
    a1 = vcmul(O0-rr, V1);
    a2 = vcmul(E0-E1, V2);
    a3 = vcmul(O0+rr, V3);
}

// Fused S4 layer, one block per channel h.
// LDS (64KB) caps occupancy at 2 blocks/CU = 4 waves/EU. amdgpu_waves_per_eu(4,4)
// pins the register allocator to that SAME occupancy -> 128-VGPR budget, no spill.
// (R5: launch_bounds min-waves=4 still let the allocator target 8 waves/EU ->
//  64 VGPRs + 127MB/dispatch scratch spill; this attribute is the fix.)
__global__ void __launch_bounds__(NT)
__attribute__((amdgpu_waves_per_eu(4, 4)))
s4_fused(const float* __restrict__ u,
         const float* __restrict__ Lre, const float* __restrict__ Lim,
         const float* __restrict__ Pre, const float* __restrict__ Pim,
         const float* __restrict__ Bre, const float* __restrict__ Bim,
         const float* __restrict__ Cin, const float* __restrict__ Din,
         const float* __restrict__ logstep,
         float* __restrict__ out)
{
    __shared__ v2 buf[8192];   // 64 KB -> 2 blocks/CU
    const int tid = threadIdx.x;
    const int h = blockIdx.x;

    // ---- P0: params in upper half (dead after P1) ----
    v2* par = buf + 4096;
    if (tid < 64) {
        const int n = tid;
        float lre = fminf(Lre[h*64+n], -1e-4f);
        float lim = Lim[h*64+n];
        par[n] = (v2){lre, lim};
        float pr = Pre[h*64+n], pi = Pim[h*64+n];
        float br = Bre[h*64+n], bi = Bim[h*64+n];
        float cr = Cin[h*128+2*n], ci = Cin[h*128+2*n+1];
        v2 cc = (v2){cr, -ci};
        par[64+n]  = vcmul(cc, (v2){br, bi});     // w00 = conj(C)*B
        par[128+n] = vcmul(cc, (v2){pr, pi});     // w01 = conj(C)*P
        v2 pc = (v2){pr, -pi};
        par[192+n] = vcmul(pc, (v2){br, bi});     // w10 = conj(P)*B
        par[256+n] = (v2){pr*pr + pi*pi, 0.0f};   // w11 = |P|^2 (real)
    }
    __syncthreads();

    const float step = expf(logstep[h]);
    const float tos  = 2.0f / step;

    // ---- P1: Cauchy kernel (two half-passes of 4 l's) ----
    #pragma unroll 1
    for (int hp = 0; hp < 2; ++hp) {
        v2 g[4], cf[4], k00[4], k01[4], k10[4], k11[4];
        const int lbase = hp*(4*NT);
        #pragma unroll
        for (int i = 0; i < 4; ++i) {
            int l = lbase + i*NT + tid;
            // mimic reference's f32 angle; sin/cos rounded from double (critical near l=2048)
            float ang = -6.2831855f * ((float)l * (1.0f/4096.0f));
            double ds, dc;
            sincos((double)ang, &ds, &dc);
            float Omx = (float)dc, Omy = (float)ds;
            float nx = 1.0f-Omx, ny = -Omy;
            float dx = 1.0f+Omx, dy =  Omy;
            float dinv = 1.0f/(dx*dx + dy*dy);
            g[i]  = (v2){tos*((nx*dx+ny*dy)*dinv), tos*((ny*dx-nx*dy)*dinv)};
            cf[i] = (v2){2.0f*dx*dinv, -2.0f*dy*dinv};
            k00[i]=(v2)(0.0f); k01[i]=(v2)(0.0f); k10[i]=(v2)(0.0f); k11[i]=(v2)(0.0f);
        }
        #pragma unroll 2
        for (int n = 0; n < 64; ++n) {
            v2 lam = par[n];
            v2 w00 = par[64+n], w01 = par[128+n], w10 = par[192+n];
            float w11r = par[256+n].x;
            #pragma unroll
            for (int i = 0; i < 4; ++i) {
                v2 d = g[i] - lam;
                float inv = __builtin_amdgcn_rcpf(d.x*d.x + d.y*d.y);
                v2 p  = d * inv;
                v2 cp = (v2){p.x, -p.y};                         // 1/(g-lam)
                v2 rp = (v2){p.y,  p.x};
                k00[i] = vfma1(w00.y, rp, vfma1(w00.x, cp, k00[i]));
                k01[i] = vfma1(w01.y, rp, vfma1(w01.x, cp, k01[i]));
                k10[i] = vfma1(w10.y, rp, vfma1(w10.x, cp, k10[i]));
                k11[i] = vfma1(w11r,  cp, k11[i]);
            }
        }
        #pragma unroll
        for (int i = 0; i < 4; ++i) {
            int l = lbase + i*NT + tid;
            v2 opk = (v2){1.0f + k11[i].x, k11[i].y};
            float iv = 1.0f/(opk.x*opk.x + opk.y*opk.y);
            v2 r11 = vconj(opk) * iv;
            v2 t  = vcmul(vcmul(k01[i], r11), k10[i]);
            buf[SW(d8r4(l))] = vcmul(cf[i], k00[i] - t);   // scatter for radix-8 DIT
        }
    }
    __syncthreads();

    // ---- P2: ifft4096 = 4 radix-8 DIT passes -> K*4096 natural ----
    r8_dit_inv<1,  false>(buf, tid);
    r8_dit_inv<8,  true >(buf, tid);
    r8_dit_inv<64, true >(buf, tid);
    r8_dit_inv<512,true >(buf, tid);

    // ---- P3: pack z = u + i*K, zero-pad ----
    {
        float kv[8], uval[8];
        #pragma unroll
        for (int i = 0; i < 8; ++i) {
            int l = i*NT + tid;
            kv[i]   = buf[SW(l)].x * (1.0f/4096.0f);
            uval[i] = u[h*4096 + l];
        }
        __syncthreads();
        #pragma unroll
        for (int i = 0; i < 8; ++i) {
            int l = i*NT + tid;
            buf[SW(l)]      = (v2){uval[i], kv[i]};
            buf[SW(l+4096)] = (v2)(0.0f);
        }
    }
    __syncthreads();

    // ---- P4: forward fft8192, 4 register-blocked passes; layer sequence and output
    //      placement identical to [r2; r4 q=1024,256,64,16,4,1] => Z[k] at (k&1)<<12 | d4r6(k>>1).
    const float RH = 0.70710678f;
    const v2 C16 = (v2){0.92387953f, -0.38268343f};   // e^{-i*pi/8}
    {   // pass A: r2(half=4096) + r4(q=1024); 16 points/thread (j = tid, tid+512)
        const float fm = -6.2831853072f / 8192.0f;
        float sb, cb; __sincosf(fm*(float)tid, &sb, &cb);
        v2 w[2]; w[0] = (v2){cb, sb}; w[1] = vcmul(w[0], C16);  // W^-(t+512) = W^-t * e^{-i pi/8}
        #pragma unroll
        for (int jj = 0; jj < 2; ++jj) {
            int j = tid + 512*jj;
            v2 W = w[jj];
            v2 x[4], y[4];
            #pragma unroll
            for (int k = 0; k < 4; ++k) { x[k] = buf[SW(j + 1024*k)]; y[k] = buf[SW(j + 1024*k + 4096)]; }
            v2 a[4], b[4];
            #pragma unroll
            for (int k = 0; k < 4; ++k) { a[k] = x[k] + y[k]; b[k] = vcmul(x[k] - y[k], W); }
            // * omega8^{-k}:  k=1: (1-i)/sqrt2, k=2: -i, k=3: (-1-i)/sqrt2
            b[1] = RH*(b[1] - vrot(b[1]));
            b[2] = (v2){b[2].y, -b[2].x};
            b[3] = (-RH)*(b[3] + vrot(b[3]));
            v2 V1 = vcmul(W, W), V2 = vcmul(V1, V1), V3 = vcmul(V1, V2);  // W_4096^{-j}
            r4dif(a[0], a[1], a[2], a[3], V1, V2, V3);
            r4dif(b[0], b[1], b[2], b[3], V1, V2, V3);
            #pragma unroll
            for (int m = 0; m < 4; ++m) { buf[SW(j + 1024*m)] = a[m]; buf[SW(j + 1024*m + 4096)] = b[m]; }
        }
        __syncthreads();
    }
    {   // pass B: r4(q=256) + r4(q=64); 16 pts/thread
        int r = tid & 63, beta = tid >> 6;
        int base = 1024*beta + r;
        v2 x[16];
        #pragma unroll
        for (int m = 0; m < 4; ++m)
            #pragma unroll
            for (int s = 0; s < 4; ++s) x[4*m+s] = buf[SW(base + 256*m + 64*s)];
        const float fm = -6.2831853072f / 1024.0f;
        float sb, cb; __sincosf(fm*(float)r, &sb, &cb);
        v2 tau = (v2){cb, sb};
        v2 T = tau;
        #pragma unroll
        for (int s = 0; s < 4; ++s) {      // layer q=256: j = r+64s, twiddle T = W_1024^{-j}
            v2 T2 = vcmul(T,T), T3 = vcmul(T,T2);
            r4dif(x[0+s], x[4+s], x[8+s], x[12+s], T, T2, T3);
            T = vcmul(T, C16);             // W_1024^{-64} = e^{-i pi/8}
        }
        v2 tt = vcmul(tau,tau);
        v2 U1 = vcmul(tt,tt);              // tau^4 = W_256^{-r}
        v2 U2 = vcmul(U1,U1), U3 = vcmul(U1,U2);
        #pragma unroll
        for (int m = 0; m < 4; ++m)        // layer q=64: j = r
            r4dif(x[4*m], x[4*m+1], x[4*m+2], x[4*m+3], U1, U2, U3);
        #pragma unroll
        for (int m = 0; m < 4; ++m)
            #pragma unroll
            for (int s = 0; s < 4; ++s) buf[SW(base + 256*m + 64*s)] = x[4*m+s];
        __syncthreads();
    }
    {   // pass C: r4(q=16) + r4(q=4); 16 pts/thread
        int r = tid & 3, B = tid >> 2;
        int base = 64*B + r;
        v2 x[16];
        #pragma unroll
        for (int m = 0; m < 4; ++m)
            #pragma unroll
            for (int s = 0; s < 4; ++s) x[4*m+s] = buf[SW(base + 16*m + 4*s)];
        const float fm = -6.2831853072f / 64.0f;
        float sb, cb; __sincosf(fm*(float)r, &sb, &cb);
        v2 vv = (v2){cb, sb};
        v2 T = vv;
        #pragma unroll
        for (int s = 0; s < 4; ++s) {      // layer q=16: j = r+4s, twiddle W_64^{-j}
            v2 T2 = vcmul(T,T), T3 = vcmul(T,T2);
            r4dif(x[0+s], x[4+s], x[8+s], x[12+s], T, T2, T3);
            T = vcmul(T, C16);             // W_64^{-4} = e^{-i pi/8}
        }
        v2 tt = vcmul(vv,vv);
        v2 U1 = vcmul(tt,tt);              // v^4 = W_16^{-r}
        v2 U2 = vcmul(U1,U1), U3 = vcmul(U1,U2);
        #pragma unroll
        for (int m = 0; m < 4; ++m)        // layer q=4: j = r
            r4dif(x[4*m], x[4*m+1], x[4*m+2], x[4*m+3], U1, U2, U3);
        #pragma unroll
        for (int m = 0; m < 4; ++m)
            #pragma unroll
            for (int s = 0; s < 4; ++s) buf[SW(base + 16*m + 4*s)] = x[4*m+s];
        __syncthreads();
    }
    {   // pass D: r4(q=1), twiddle-free; 4 butterflies/thread
        #pragma unroll
        for (int i = 0; i < 4; ++i) {
            int e = 4*(tid + 512*i);
            v2 a0 = buf[SW(e)], a1 = buf[SW(e+1)], a2 = buf[SW(e+2)], a3 = buf[SW(e+3)];
            v2 E0 = a0+a2, E1 = a1+a3, O0 = a0-a2, O1 = a1-a3, rr = vrot(O1);
            buf[SW(e)]   = E0+E1;
            buf[SW(e+1)] = O0-rr;
            buf[SW(e+2)] = E0-E1;
            buf[SW(e+3)] = O0+rr;
        }
        __syncthreads();
    }

    // ---- P5: unpack + multiply + half-size-inverse pack ----
    // Z[k] lives at (k&1)<<12 | d4r6(k>>1).
    {
        const float fm = 6.2831853072f / 8192.0f;   // W = e^{+2pi i/8192}
        v2 v[8];
        #pragma unroll 1
        for (int i = 0; i < 8; ++i) {
            int r  = i*NT + tid;                   // 0..4095
            float sw_, cw_; __sincosf(fm*(float)r, &sw_, &cw_);
            v2 cur = (v2){cw_, sw_};
            int k1 = r,        k1c = (8192 - r) & 8191;
            int k2 = r + 4096, k2c = 4096 - r;
            v2 za = buf[SW(((k1 &1)<<12) + d4r6(k1 >>1))];
            v2 zb = buf[SW(((k1c&1)<<12) + d4r6(k1c>>1))];
            v2 zc = buf[SW(((k2 &1)<<12) + d4r6(k2 >>1))];
            v2 zd = buf[SW(((k2c&1)<<12) + d4r6(k2c>>1))];
            v2 U1 = 0.5f*(za + vconj(zb));
            v2 K1 = -0.5f*vrot(za - vconj(zb));
            v2 Yr = vcmul(U1, K1);                               // Y[r]
            v2 U2 = 0.5f*(zc + vconj(zd));
            v2 K2 = -0.5f*vrot(zc - vconj(zd));
            v2 Ys = vcmul(U2, K2);                               // Y[r+4096]
            v[i] = (Yr + Ys) + vrot(vcmul(cur, Yr - Ys));        // A + i*W^r*(Yr-Ys)
        }
        __syncthreads();   // all reads done before any scatter write
        #pragma unroll
        for (int i = 0; i < 8; ++i) {
            int r = i*NT + tid;
            buf[SW(d8r4(r))] = v[i];                // scatter for radix-8 DIT
        }
        __syncthreads();
    }

    // ---- P6: ifft4096 = 4 radix-8 DIT passes -> p[n] = y[2n] + i*y[2n+1] ----
    r8_dit_inv<1,  false>(buf, tid);
    r8_dit_inv<8,  true >(buf, tid);
    r8_dit_inv<64, true >(buf, tid);
    r8_dit_inv<512,true >(buf, tid);

    // ---- P7: epilogue, float2 loads/stores ----
    {
        const float Dh = Din[h];
        const float sc = 1.0f / 8192.0f;
        const v2* u2 = (const v2*)(u + h*4096);
        v2*     out2 = (v2*)(out + h*4096);
        #pragma unroll
        for (int i = 0; i < 4; ++i) {
            int n = i*NT + tid;                   // outputs 2n, 2n+1
            v2 p  = buf[SW(n)];
            v2 uu = u2[n];
            out2[n] = sc*p + Dh*uu;
        }
    }
}

extern "C" void kernel_launch(void* const* d_in, const int* in_sizes, int n_in,
                              void* d_out, int out_size, void* d_ws, size_t ws_size,
                              hipStream_t stream)
{
    const float* u       = (const float*)d_in[0];
    const float* Lre     = (const float*)d_in[1];
    const float* Lim     = (const float*)d_in[2];
    const float* Pre     = (const float*)d_in[3];
    const float* Pim     = (const float*)d_in[4];
    const float* Bre     = (const float*)d_in[5];
    const float* Bim     = (const float*)d_in[6];
    const float* Cin     = (const float*)d_in[7];
    const float* Din     = (const float*)d_in[8];
    const float* logstep = (const float*)d_in[9];
    float* out = (float*)d_out;
    const int H = in_sizes[8];  // D is [H,1]
    hipLaunchKernelGGL(s4_fused, dim3(H), dim3(NT), 0, stream,
                       u, Lre, Lim, Pre, Pim, Bre, Bim, Cin, Din, logstep, out);
}

// Round 8
// 173.289 us; speedup vs baseline: 1.0338x; 1.0338x over previous
//
#include <hip/hip_runtime.h>
#include <math.h>

#define NT 512   // threads per block; 512 blocks (one per channel h)

// Packed f32 pair: LLVM lowers arithmetic on this to v_pk_*_f32 (VOP3P) on gfx950.
typedef float v2 __attribute__((ext_vector_type(2)));

__device__ __forceinline__ v2 vrot(v2 a){ return (v2){-a.y, a.x}; }            // i*a
__device__ __forceinline__ v2 vconj(v2 a){ return (v2){a.x, -a.y}; }
__device__ __forceinline__ v2 vcmul(v2 a, v2 b){ return a.x*b + a.y*vrot(b); } // complex mul: 2 pk_fma
__device__ __forceinline__ v2 vfma1(float s, v2 v, v2 acc){                    // acc + s*v: 1 pk_fma
    return (v2){ __builtin_fmaf(s, v.x, acc.x), __builtin_fmaf(s, v.y, acc.y) };
}

// XOR bank swizzle: float2 elements -> bank = (2e)%32 depends on e mod 16.
__device__ __forceinline__ int SW(int e){ return e ^ (((e>>5) ^ (e>>9)) & 15); }

// base-8 digit reversal of a 12-bit index
__device__ __forceinline__ int d8r4(int x){
    return ((x&7)<<9) | (((x>>3)&7)<<6) | (((x>>6)&7)<<3) | ((x>>9)&7);
}

// ---- 8-point DFT, inverse sign (sigma=+1). y_m = sum_k t_k w^{mk}, w=e^{+i pi/4}
__device__ __forceinline__ void dft8_inv(v2 t[8], v2 y[8]) {
    const float RH = 0.70710678f;
    v2 p  = t[0]+t[4], m  = t[0]-t[4], q  = t[2]+t[6], r  = t[2]-t[6];
    v2 rr = vrot(r);
    v2 E0 = p+q, E2 = p-q, E1 = m+rr, E3 = m-rr;
    v2 p2 = t[1]+t[5], m2 = t[1]-t[5], q2 = t[3]+t[7], r2 = t[3]-t[7];
    v2 rr2 = vrot(r2);
    v2 O0 = p2+q2, O2 = p2-q2, O1 = m2+rr2, O3 = m2-rr2;
    v2 W1O = RH*(O1 + vrot(O1));        // w^1 * O1
    v2 W2O = vrot(O2);                  // w^2 = i
    v2 W3O = vrot(RH*(O3 + vrot(O3)));  // w^3 = i*w
    y[0] = E0 + O0;  y[4] = E0 - O0;
    y[1] = E1 + W1O; y[5] = E1 - W1O;
    y[2] = E2 + W2O; y[6] = E2 - W2O;
    y[3] = E3 + W3O; y[7] = E3 - W3O;
}

// ---- 8-point DFT, forward sign (sigma=-1). y_m = sum_k t_k w^{mk}, w=e^{-i pi/4}
__device__ __forceinline__ void dft8_fwd(v2 t[8], v2 y[8]) {
    const float RH = 0.70710678f;
    v2 p  = t[0]+t[4], m  = t[0]-t[4], q  = t[2]+t[6], r  = t[2]-t[6];
    v2 rr = vrot(r);
    v2 E0 = p+q, E2 = p-q, E1 = m-rr, E3 = m+rr;
    v2 p2 = t[1]+t[5], m2 = t[1]-t[5], q2 = t[3]+t[7], r2 = t[3]-t[7];
    v2 rr2 = vrot(r2);
    v2 O0 = p2+q2, O2 = p2-q2, O1 = m2-rr2, O3 = m2+rr2;
    v2 W1O = RH*(O1 - vrot(O1));          // w^1 * O1, w=(1-i)/sqrt2
    v2 W2O = (v2){O2.y, -O2.x};           // w^2 = -i
    v2 W3O = (-RH)*(O3 + vrot(O3));       // w^3 = (-1-i)/sqrt2
    y[0] = E0 + O0;  y[4] = E0 - O0;
    y[1] = E1 + W1O; y[5] = E1 - W1O;
    y[2] = E2 + W2O; y[6] = E2 - W2O;
    y[3] = E3 + W3O; y[7] = E3 - W3O;
}

// ---- radix-8 DIT pass, inverse (sigma=+1), in-place over 4096 elems.
// Q in {1,8,64,512}; input base-8 digit-reversed, output natural after Q=512.
// One butterfly per thread (512 butterflies): t[8]+twiddles ~46 VGPRs live.
template<int Q, bool TW>
__device__ __forceinline__ void r8_dit_inv(v2* buf, int tid) {
    int j = tid & (Q-1);
    int base = 8*tid - 7*j;
    v2 t[8];
    #pragma unroll
    for (int k = 0; k < 8; ++k) t[k] = buf[SW(base + k*Q)];
    if (TW) {
        const float fm = 6.2831853072f / (float)(8*Q);
        float sb, cb; __sincosf(fm*(float)j, &sb, &cb);
        v2 W1 = (v2){cb, sb};
        v2 W2 = vcmul(W1,W1), W3 = vcmul(W1,W2), W4 = vcmul(W2,W2),
           W5 = vcmul(W2,W3), W6 = vcmul(W3,W3), W7 = vcmul(W3,W4);
        t[1]=vcmul(t[1],W1); t[2]=vcmul(t[2],W2); t[3]=vcmul(t[3],W3);
        t[4]=vcmul(t[4],W4); t[5]=vcmul(t[5],W5); t[6]=vcmul(t[6],W6);
        t[7]=vcmul(t[7],W7);
    }
    v2 y[8];
    dft8_inv(t, y);
    #pragma unroll
    for (int m = 0; m < 8; ++m) buf[SW(base + m*Q)] = y[m];
    __syncthreads();
}

// ---- radix-8 DIF pass, forward (sigma=-1), applied to BOTH 4096-halves of buf.
// Butterfly first, then y[m] *= W_{8Q}^{-j*m}; output base-8 digit-reversed.
// Same j for both halves -> twiddles computed once. One butterfly live at a time.
template<int Q>
__device__ __forceinline__ void r8_dif_fwd(v2* buf, int tid) {
    int j = tid & (Q-1);
    int baseL = 8*tid - 7*j;
    v2 W1=(v2){1.0f,0.0f},W2=W1,W3=W1,W4=W1,W5=W1,W6=W1,W7=W1;
    if (Q > 1) {
        const float fm = -6.2831853072f / (float)(8*Q);
        float sb, cb; __sincosf(fm*(float)j, &sb, &cb);
        W1 = (v2){cb, sb};
        W2 = vcmul(W1,W1); W3 = vcmul(W1,W2); W4 = vcmul(W2,W2);
        W5 = vcmul(W2,W3); W6 = vcmul(W3,W3); W7 = vcmul(W3,W4);
    }
    #pragma unroll 1
    for (int hh = 0; hh < 2; ++hh) {
        int base = baseL + (hh << 12);
        v2 t[8];
        #pragma unroll
        for (int k = 0; k < 8; ++k) t[k] = buf[SW(base + k*Q)];
        v2 y[8];
        dft8_fwd(t, y);
        if (Q > 1) {
            y[1]=vcmul(y[1],W1); y[2]=vcmul(y[2],W2); y[3]=vcmul(y[3],W3);
            y[4]=vcmul(y[4],W4); y[5]=vcmul(y[5],W5); y[6]=vcmul(y[6],W6);
            y[7]=vcmul(y[7],W7);
        }
        #pragma unroll
        for (int m = 0; m < 8; ++m) buf[SW(base + m*Q)] = y[m];
    }
    __syncthreads();
}

// Fused S4 layer, one block per channel h.
// All phases sized for the backend's observed 64-VGPR budget (R5/R6: 16-point
// register blocks at VGPR 64 -> 127 MB/dispatch scratch spill; 8-point max here).
__global__ void __launch_bounds__(NT)
s4_fused(const float* __restrict__ u,
         const float* __restrict__ Lre, const float* __restrict__ Lim,
         const float* __restrict__ Pre, const float* __restrict__ Pim,
         const float* __restrict__ Bre, const float* __restrict__ Bim,
         const float* __restrict__ Cin, const float* __restrict__ Din,
         const float* __restrict__ logstep,
         float* __restrict__ out)
{
    __shared__ v2 buf[8192];   // 64 KB -> 2 blocks/CU
    const int tid = threadIdx.x;
    const int h = blockIdx.x;

    // ---- P0: params in upper half (dead after P1) ----
    v2* par = buf + 4096;
    if (tid < 64) {
        const int n = tid;
        float lre = fminf(Lre[h*64+n], -1e-4f);
        float lim = Lim[h*64+n];
        par[n] = (v2){lre, lim};
        float pr = Pre[h*64+n], pi = Pim[h*64+n];
        float br = Bre[h*64+n], bi = Bim[h*64+n];
        float cr = Cin[h*128+2*n], ci = Cin[h*128+2*n+1];
        v2 cc = (v2){cr, -ci};
        par[64+n]  = vcmul(cc, (v2){br, bi});     // w00 = conj(C)*B
        par[128+n] = vcmul(cc, (v2){pr, pi});     // w01 = conj(C)*P
        v2 pc = (v2){pr, -pi};
        par[192+n] = vcmul(pc, (v2){br, bi});     // w10 = conj(P)*B
        par[256+n] = (v2){pr*pr + pi*pi, 0.0f};   // w11 = |P|^2 (real)
    }
    __syncthreads();

    const float step = expf(logstep[h]);
    const float tos  = 2.0f / step;

    // ---- P1: Cauchy kernel (two half-passes of 4 l's; unroll 1 = R3's no-spill config) ----
    #pragma unroll 1
    for (int hp = 0; hp < 2; ++hp) {
        v2 g[4], cf[4], k00[4], k01[4], k10[4], k11[4];
        const int lbase = hp*(4*NT);
        #pragma unroll
        for (int i = 0; i < 4; ++i) {
            int l = lbase + i*NT + tid;
            // mimic reference's f32 angle; sin/cos rounded from double (critical near l=2048)
            float ang = -6.2831855f * ((float)l * (1.0f/4096.0f));
            double ds, dc;
            sincos((double)ang, &ds, &dc);
            float Omx = (float)dc, Omy = (float)ds;
            float nx = 1.0f-Omx, ny = -Omy;
            float dx = 1.0f+Omx, dy =  Omy;
            float dinv = 1.0f/(dx*dx + dy*dy);
            g[i]  = (v2){tos*((nx*dx+ny*dy)*dinv), tos*((ny*dx-nx*dy)*dinv)};
            cf[i] = (v2){2.0f*dx*dinv, -2.0f*dy*dinv};
            k00[i]=(v2)(0.0f); k01[i]=(v2)(0.0f); k10[i]=(v2)(0.0f); k11[i]=(v2)(0.0f);
        }
        #pragma unroll 1
        for (int n = 0; n < 64; ++n) {
            v2 lam = par[n];
            v2 w00 = par[64+n], w01 = par[128+n], w10 = par[192+n];
            float w11r = par[256+n].x;
            #pragma unroll
            for (int i = 0; i < 4; ++i) {
                v2 d = g[i] - lam;
                float inv = __builtin_amdgcn_rcpf(d.x*d.x + d.y*d.y);
                v2 p  = d * inv;
                v2 cp = (v2){p.x, -p.y};                         // 1/(g-lam)
                v2 rp = (v2){p.y,  p.x};
                k00[i] = vfma1(w00.y, rp, vfma1(w00.x, cp, k00[i]));
                k01[i] = vfma1(w01.y, rp, vfma1(w01.x, cp, k01[i]));
                k10[i] = vfma1(w10.y, rp, vfma1(w10.x, cp, k10[i]));
                k11[i] = vfma1(w11r,  cp, k11[i]);
            }
        }
        #pragma unroll
        for (int i = 0; i < 4; ++i) {
            int l = lbase + i*NT + tid;
            v2 opk = (v2){1.0f + k11[i].x, k11[i].y};
            float iv = 1.0f/(opk.x*opk.x + opk.y*opk.y);
            v2 r11 = vconj(opk) * iv;
            v2 t  = vcmul(vcmul(k01[i], r11), k10[i]);
            buf[SW(d8r4(l))] = vcmul(cf[i], k00[i] - t);   // scatter for radix-8 DIT
        }
    }
    __syncthreads();

    // ---- P2: ifft4096 = 4 radix-8 DIT passes -> K*4096 natural ----
    r8_dit_inv<1,  false>(buf, tid);
    r8_dit_inv<8,  true >(buf, tid);
    r8_dit_inv<64, true >(buf, tid);
    r8_dit_inv<512,true >(buf, tid);

    // ---- P3: pack z = u + i*K, zero-pad ----
    {
        float kv[8], uval[8];
        #pragma unroll
        for (int i = 0; i < 8; ++i) {
            int l = i*NT + tid;
            kv[i]   = buf[SW(l)].x * (1.0f/4096.0f);
            uval[i] = u[h*4096 + l];
        }
        __syncthreads();
        #pragma unroll
        for (int i = 0; i < 8; ++i) {
            int l = i*NT + tid;
            buf[SW(l)]      = (v2){uval[i], kv[i]};
            buf[SW(l+4096)] = (v2)(0.0f);
        }
    }
    __syncthreads();

    // ---- P4: forward fft8192 = r2 DIF stage + 4 radix-8 DIF stages per half.
    //      Z[k] lands at ((k&1)<<12) + d8r4(k>>1).
    {
        const float fm = -6.2831853072f / 8192.0f;
        #pragma unroll 1
        for (int i = 0; i < 8; ++i) {
            int j = i*NT + tid;
            float sb, cb; __sincosf(fm*(float)j, &sb, &cb);
            v2 W = (v2){cb, sb};
            int a0 = SW(j), a1 = SW(j+4096);
            v2 a = buf[a0], c = buf[a1];
            buf[a0] = a + c;
            buf[a1] = vcmul(a - c, W);   // * W_8192^{-j}
        }
        __syncthreads();
    }
    r8_dif_fwd<512>(buf, tid);
    r8_dif_fwd<64 >(buf, tid);
    r8_dif_fwd<8  >(buf, tid);
    r8_dif_fwd<1  >(buf, tid);

    // ---- P5: unpack + multiply + half-size-inverse pack ----
    // Z[k] lives at ((k&1)<<12) + d8r4(k>>1).
    {
        const float fm = 6.2831853072f / 8192.0f;   // W = e^{+2pi i/8192}
        v2 v[8];
        #pragma unroll 1
        for (int i = 0; i < 8; ++i) {
            int r  = i*NT + tid;                   // 0..4095
            float sw_, cw_; __sincosf(fm*(float)r, &sw_, &cw_);
            v2 cur = (v2){cw_, sw_};
            int k1 = r,        k1c = (8192 - r) & 8191;
            int k2 = r + 4096, k2c = 4096 - r;
            v2 za = buf[SW(((k1 &1)<<12) + d8r4(k1 >>1))];
            v2 zb = buf[SW(((k1c&1)<<12) + d8r4(k1c>>1))];
            v2 zc = buf[SW(((k2 &1)<<12) + d8r4(k2 >>1))];
            v2 zd = buf[SW(((k2c&1)<<12) + d8r4(k2c>>1))];
            v2 U1 = 0.5f*(za + vconj(zb));
            v2 K1 = -0.5f*vrot(za - vconj(zb));
            v2 Yr = vcmul(U1, K1);                               // Y[r]
            v2 U2 = 0.5f*(zc + vconj(zd));
            v2 K2 = -0.5f*vrot(zc - vconj(zd));
            v2 Ys = vcmul(U2, K2);                               // Y[r+4096]
            v[i] = (Yr + Ys) + vrot(vcmul(cur, Yr - Ys));        // A + i*W^r*(Yr-Ys)
        }
        __syncthreads();   // all reads done before any scatter write
        #pragma unroll
        for (int i = 0; i < 8; ++i) {
            int r = i*NT + tid;
            buf[SW(d8r4(r))] = v[i];                // scatter for radix-8 DIT
        }
        __syncthreads();
    }

    // ---- P6: ifft4096 = 4 radix-8 DIT passes -> p[n] = y[2n] + i*y[2n+1] ----
    r8_dit_inv<1,  false>(buf, tid);
    r8_dit_inv<8,  true >(buf, tid);
    r8_dit_inv<64, true >(buf, tid);
    r8_dit_inv<512,true >(buf, tid);

    // ---- P7: epilogue, float2 loads/stores ----
    {
        const float Dh = Din[h];
        const float sc = 1.0f / 8192.0f;
        const v2* u2 = (const v2*)(u + h*4096);
        v2*     out2 = (v2*)(out + h*4096);
        #pragma unroll
        for (int i = 0; i < 4; ++i) {
            int n = i*NT + tid;                   // outputs 2n, 2n+1
            v2 p  = buf[SW(n)];
            v2 uu = u2[n];
            out2[n] = sc*p + Dh*uu;
        }
    }
}

extern "C" void kernel_launch(void* const* d_in, const int* in_sizes, int n_in,
                              void* d_out, int out_size, void* d_ws, size_t ws_size,
                              hipStream_t stream)
{
    const float* u       = (const float*)d_in[0];
    const float* Lre     = (const float*)d_in[1];
    const float* Lim     = (const float*)d_in[2];
    const float* Pre     = (const float*)d_in[3];
    const float* Pim     = (const float*)d_in[4];
    const float* Bre     = (const float*)d_in[5];
    const float* Bim     = (const float*)d_in[6];
    const float* Cin     = (const float*)d_in[7];
    const float* Din     = (const float*)d_in[8];
    const float* logstep = (const float*)d_in[9];
    float* out = (float*)d_out;
    const int H = in_sizes[8];  // D is [H,1]
    hipLaunchKernelGGL(s4_fused, dim3(H), dim3(NT), 0, stream,
                       u, Lre, Lim, Pre, Pim, Bre, Bim, Cin, Din, logstep, out);
}

// Round 9
// 171.871 us; speedup vs baseline: 1.0423x; 1.0082x over previous
//
#include <hip/hip_runtime.h>
#include <math.h>

#define NT 512   // threads per block; 512 blocks (one per channel h)

// Packed f32 pair: LLVM lowers arithmetic on this to v_pk_*_f32 (VOP3P) on gfx950.
typedef float v2 __attribute__((ext_vector_type(2)));

__device__ __forceinline__ v2 vrot(v2 a){ return (v2){-a.y, a.x}; }            // i*a
__device__ __forceinline__ v2 vconj(v2 a){ return (v2){a.x, -a.y}; }
__device__ __forceinline__ v2 vcmul(v2 a, v2 b){ return a.x*b + a.y*vrot(b); } // complex mul: 2 pk_fma
__device__ __forceinline__ v2 vfma1(float s, v2 v, v2 acc){                    // acc + s*v: 1 pk_fma
    return (v2){ __builtin_fmaf(s, v.x, acc.x), __builtin_fmaf(s, v.y, acc.y) };
}

// XOR bank swizzle: float2 elements -> bank = (2e)%32 depends on e mod 16.
__device__ __forceinline__ int SW(int e){ return e ^ (((e>>5) ^ (e>>9)) & 15); }

// base-8 digit reversal of a 12-bit index
__device__ __forceinline__ int d8r4(int x){
    return ((x&7)<<9) | (((x>>3)&7)<<6) | (((x>>6)&7)<<3) | ((x>>9)&7);
}
// base-8 digit reversal of a 9-bit index (thread id <-> butterfly block)
__device__ __forceinline__ int rev3(int t){
    return ((t&7)<<6) | (t&56) | ((t>>6)&7);
}

// ---- 8-point DFT, inverse sign (sigma=+1). y_m = sum_k t_k w^{mk}, w=e^{+i pi/4}
__device__ __forceinline__ void dft8_inv(v2 t[8], v2 y[8]) {
    const float RH = 0.70710678f;
    v2 p  = t[0]+t[4], m  = t[0]-t[4], q  = t[2]+t[6], r  = t[2]-t[6];
    v2 rr = vrot(r);
    v2 E0 = p+q, E2 = p-q, E1 = m+rr, E3 = m-rr;
    v2 p2 = t[1]+t[5], m2 = t[1]-t[5], q2 = t[3]+t[7], r2 = t[3]-t[7];
    v2 rr2 = vrot(r2);
    v2 O0 = p2+q2, O2 = p2-q2, O1 = m2+rr2, O3 = m2-rr2;
    v2 W1O = RH*(O1 + vrot(O1));        // w^1 * O1
    v2 W2O = vrot(O2);                  // w^2 = i
    v2 W3O = vrot(RH*(O3 + vrot(O3)));  // w^3 = i*w
    y[0] = E0 + O0;  y[4] = E0 - O0;
    y[1] = E1 + W1O; y[5] = E1 - W1O;
    y[2] = E2 + W2O; y[6] = E2 - W2O;
    y[3] = E3 + W3O; y[7] = E3 - W3O;
}

// ---- 8-point DFT, forward sign (sigma=-1).
__device__ __forceinline__ void dft8_fwd(v2 t[8], v2 y[8]) {
    const float RH = 0.70710678f;
    v2 p  = t[0]+t[4], m  = t[0]-t[4], q  = t[2]+t[6], r  = t[2]-t[6];
    v2 rr = vrot(r);
    v2 E0 = p+q, E2 = p-q, E1 = m-rr, E3 = m+rr;
    v2 p2 = t[1]+t[5], m2 = t[1]-t[5], q2 = t[3]+t[7], r2 = t[3]-t[7];
    v2 rr2 = vrot(r2);
    v2 O0 = p2+q2, O2 = p2-q2, O1 = m2-rr2, O3 = m2+rr2;
    v2 W1O = RH*(O1 - vrot(O1));          // w = (1-i)/sqrt2
    v2 W2O = (v2){O2.y, -O2.x};           // w^2 = -i
    v2 W3O = (-RH)*(O3 + vrot(O3));       // w^3 = (-1-i)/sqrt2
    y[0] = E0 + O0;  y[4] = E0 - O0;
    y[1] = E1 + W1O; y[5] = E1 - W1O;
    y[2] = E2 + W2O; y[6] = E2 - W2O;
    y[3] = E3 + W3O; y[7] = E3 - W3O;
}

// ---- twiddle application for inverse DIT butterfly: t[k] *= W^k, W = e^{+2pi i j / (8Q)}
__device__ __forceinline__ void apply_tw_inv(v2 t[8], float fm, int j) {
    float sb, cb; __sincosf(fm*(float)j, &sb, &cb);
    v2 W1 = (v2){cb, sb};
    v2 W2 = vcmul(W1,W1), W3 = vcmul(W1,W2), W4 = vcmul(W2,W2),
       W5 = vcmul(W2,W3), W6 = vcmul(W3,W3), W7 = vcmul(W3,W4);
    t[1]=vcmul(t[1],W1); t[2]=vcmul(t[2],W2); t[3]=vcmul(t[3],W3);
    t[4]=vcmul(t[4],W4); t[5]=vcmul(t[5],W5); t[6]=vcmul(t[6],W6);
    t[7]=vcmul(t[7],W7);
}

// ---- radix-8 DIT pass, inverse, in-place over 4096 elems (standalone middle passes).
template<int Q>
__device__ __forceinline__ void r8_dit_inv(v2* buf, int tid) {
    int j = tid & (Q-1);
    int base = 8*tid - 7*j;
    v2 t[8];
    #pragma unroll
    for (int k = 0; k < 8; ++k) t[k] = buf[SW(base + k*Q)];
    apply_tw_inv(t, 6.2831853072f / (float)(8*Q), j);
    v2 y[8];
    dft8_inv(t, y);
    #pragma unroll
    for (int m = 0; m < 8; ++m) buf[SW(base + m*Q)] = y[m];
    __syncthreads();
}

// ---- radix-8 DIF pass, forward, applied to BOTH 4096-halves of buf.
template<int Q>
__device__ __forceinline__ void r8_dif_fwd(v2* buf, int tid) {
    int j = tid & (Q-1);
    int baseL = 8*tid - 7*j;
    v2 W1=(v2){1.0f,0.0f},W2=W1,W3=W1,W4=W1,W5=W1,W6=W1,W7=W1;
    if (Q > 1) {
        const float fm = -6.2831853072f / (float)(8*Q);
        float sb, cb; __sincosf(fm*(float)j, &sb, &cb);
        W1 = (v2){cb, sb};
        W2 = vcmul(W1,W1); W3 = vcmul(W1,W2); W4 = vcmul(W2,W2);
        W5 = vcmul(W2,W3); W6 = vcmul(W3,W3); W7 = vcmul(W3,W4);
    }
    #pragma unroll 1
    for (int hh = 0; hh < 2; ++hh) {
        int base = baseL + (hh << 12);
        v2 t[8];
        #pragma unroll
        for (int k = 0; k < 8; ++k) t[k] = buf[SW(base + k*Q)];
        v2 y[8];
        dft8_fwd(t, y);
        if (Q > 1) {
            y[1]=vcmul(y[1],W1); y[2]=vcmul(y[2],W2); y[3]=vcmul(y[3],W3);
            y[4]=vcmul(y[4],W4); y[5]=vcmul(y[5],W5); y[6]=vcmul(y[6],W6);
            y[7]=vcmul(y[7],W7);
        }
        #pragma unroll
        for (int m = 0; m < 8; ++m) buf[SW(base + m*Q)] = y[m];
    }
    __syncthreads();
}

// Fused S4 layer, one block per channel h. First/last FFT passes of each
// transform are fused into the producing/consuming phase via index algebra:
// thread computing values at l = tid+512j (j=0..7) owns exactly the radix-8
// Q=1 butterfly of block 8*rev3(tid); Q=512 outputs at tid+512m are the same
// thread's pack/epilogue indices; the r2 stage of fft8192 folds into the
// zero-pad (upper input is 0). 13 -> 8 standalone LDS passes.
__global__ void __launch_bounds__(NT)
s4_fused(const float* __restrict__ u,
         const float* __restrict__ Lre, const float* __restrict__ Lim,
         const float* __restrict__ Pre, const float* __restrict__ Pim,
         const float* __restrict__ Bre, const float* __restrict__ Bim,
         const float* __restrict__ Cin, const float* __restrict__ Din,
         const float* __restrict__ logstep,
         float* __restrict__ out)
{
    __shared__ v2 buf[8192];   // 64 KB -> 2 blocks/CU
    const int tid = threadIdx.x;
    const int h = blockIdx.x;

    // ---- P0: params in upper half (dead after P1) ----
    v2* par = buf + 4096;
    if (tid < 64) {
        const int n = tid;
        float lre = fminf(Lre[h*64+n], -1e-4f);
        float lim = Lim[h*64+n];
        par[n] = (v2){lre, lim};
        float pr = Pre[h*64+n], pi = Pim[h*64+n];
        float br = Bre[h*64+n], bi = Bim[h*64+n];
        float cr = Cin[h*128+2*n], ci = Cin[h*128+2*n+1];
        v2 cc = (v2){cr, -ci};
        par[64+n]  = vcmul(cc, (v2){br, bi});     // w00 = conj(C)*B
        par[128+n] = vcmul(cc, (v2){pr, pi});     // w01 = conj(C)*P
        v2 pc = (v2){pr, -pi};
        par[192+n] = vcmul(pc, (v2){br, bi});     // w10 = conj(P)*B
        par[256+n] = (v2){pr*pr + pi*pi, 0.0f};   // w11 = |P|^2 (real)
    }
    __syncthreads();

    const float step = expf(logstep[h]);
    const float tos  = 2.0f / step;

    // ---- P1: Cauchy kernel; hp0's 4 results staged raw in LDS, hp1's kept in
    //      regs; then the P2 Q=1 butterfly runs in registers (fusion 1). ----
    v2 a4[4];
    #pragma unroll 1
    for (int hp = 0; hp < 2; ++hp) {
        v2 g[4], cf[4], k00[4], k01[4], k10[4], k11[4];
        const int lbase = hp*(4*NT);
        #pragma unroll
        for (int i = 0; i < 4; ++i) {
            int l = lbase + i*NT + tid;
            // mimic reference's f32 angle; sin/cos rounded from double (critical near l=2048)
            float ang = -6.2831855f * ((float)l * (1.0f/4096.0f));
            double ds, dc;
            sincos((double)ang, &ds, &dc);
            float Omx = (float)dc, Omy = (float)ds;
            float nx = 1.0f-Omx, ny = -Omy;
            float dx = 1.0f+Omx, dy =  Omy;
            float dinv = 1.0f/(dx*dx + dy*dy);
            g[i]  = (v2){tos*((nx*dx+ny*dy)*dinv), tos*((ny*dx-nx*dy)*dinv)};
            cf[i] = (v2){2.0f*dx*dinv, -2.0f*dy*dinv};
            k00[i]=(v2)(0.0f); k01[i]=(v2)(0.0f); k10[i]=(v2)(0.0f); k11[i]=(v2)(0.0f);
        }
        #pragma unroll 1
        for (int n = 0; n < 64; ++n) {
            v2 lam = par[n];
            v2 w00 = par[64+n], w01 = par[128+n], w10 = par[192+n];
            float w11r = par[256+n].x;
            #pragma unroll
            for (int i = 0; i < 4; ++i) {
                v2 d = g[i] - lam;
                float inv = __builtin_amdgcn_rcpf(d.x*d.x + d.y*d.y);
                v2 p  = d * inv;
                v2 cp = (v2){p.x, -p.y};                         // 1/(g-lam)
                v2 rp = (v2){p.y,  p.x};
                k00[i] = vfma1(w00.y, rp, vfma1(w00.x, cp, k00[i]));
                k01[i] = vfma1(w01.y, rp, vfma1(w01.x, cp, k01[i]));
                k10[i] = vfma1(w10.y, rp, vfma1(w10.x, cp, k10[i]));
                k11[i] = vfma1(w11r,  cp, k11[i]);
            }
        }
        #pragma unroll
        for (int i = 0; i < 4; ++i) {
            v2 opk = (v2){1.0f + k11[i].x, k11[i].y};
            float iv = 1.0f/(opk.x*opk.x + opk.y*opk.y);
            v2 r11 = vconj(opk) * iv;
            v2 t  = vcmul(vcmul(k01[i], r11), k10[i]);
            v2 res = vcmul(cf[i], k00[i] - t);               // atRoots[l], l = tid+512*(4hp+i)
            if (hp == 0) buf[SW(tid + 512*i)] = res;         // stage raw
            else         a4[i] = res;
        }
    }
    {   // fused P2 Q=1 butterfly: t[k] = atRoots[tid + 512k]
        v2 t[8];
        #pragma unroll
        for (int k = 0; k < 4; ++k) t[k] = buf[SW(tid + 512*k)];   // own raw stage
        #pragma unroll
        for (int k = 0; k < 4; ++k) t[4+k] = a4[k];
        __syncthreads();                    // all raw reads done before any butterfly write
        v2 y[8];
        dft8_inv(t, y);
        int tb8 = 8*rev3(tid);
        #pragma unroll
        for (int m = 0; m < 8; ++m) buf[SW(tb8 + m)] = y[m];
    }
    __syncthreads();

    // ---- P2: ifft4096 middle passes ----
    r8_dit_inv<8 >(buf, tid);
    r8_dit_inv<64>(buf, tid);

    // ---- P3: fused P2-Q512 butterfly + pack z = u + i*K + r2 stage of fft8192
    //      (upper input is the zero pad: buf[l]=z, buf[l+4096]=z*W_8192^{-l}). ----
    {
        v2 t[8];
        #pragma unroll
        for (int k = 0; k < 8; ++k) t[k] = buf[SW(tid + 512*k)];
        apply_tw_inv(t, 6.2831853072f / 4096.0f, tid);
        v2 y[8];
        dft8_inv(t, y);                          // y[m] = K*4096 at l = tid+512m
        float uval[8];
        const float* up = u + h*4096;
        #pragma unroll
        for (int m = 0; m < 8; ++m) uval[m] = up[tid + 512*m];
        __syncthreads();                         // all Q512 reads done before pack writes
        float s2, c2; __sincosf(-6.2831853072f/8192.0f*(float)tid, &s2, &c2);
        v2 cur = (v2){c2, s2};                   // W_8192^{-tid}
        const v2 C16n = (v2){0.92387953f, -0.38268343f};   // e^{-i pi/8} = W_8192^{-512}
        #pragma unroll
        for (int m = 0; m < 8; ++m) {
            int l = tid + 512*m;
            v2 z = (v2){uval[m], y[m].x * (1.0f/4096.0f)};
            buf[SW(l)]      = z;
            buf[SW(l+4096)] = vcmul(z, cur);
            cur = vcmul(cur, C16n);
        }
    }
    __syncthreads();

    // ---- P4: forward fft8192 remaining stages (r2 folded into P3).
    //      Z[k] lands at ((k&1)<<12) + d8r4(k>>1).
    r8_dif_fwd<512>(buf, tid);
    r8_dif_fwd<64 >(buf, tid);
    r8_dif_fwd<8  >(buf, tid);
    r8_dif_fwd<1  >(buf, tid);

    // ---- P5: unpack + multiply + half-size-inverse pack, fused with P6 Q=1
    //      butterfly (v[i] for r = tid+512i are exactly block 8*rev3(tid)'s inputs).
    {
        float sb, cb; __sincosf(6.2831853072f/8192.0f*(float)tid, &sb, &cb);
        v2 cur = (v2){cb, sb};                   // W_8192^{+tid}
        const v2 C16p = (v2){0.92387953f, 0.38268343f};    // e^{+i pi/8}
        v2 v[8];
        #pragma unroll 1
        for (int i = 0; i < 8; ++i) {
            int r  = i*NT + tid;                 // 0..4095
            int k1 = r,        k1c = (8192 - r) & 8191;
            int k2 = r + 4096, k2c = 4096 - r;
            v2 za = buf[SW(((k1 &1)<<12) + d8r4(k1 >>1))];
            v2 zb = buf[SW(((k1c&1)<<12) + d8r4(k1c>>1))];
            v2 zc = buf[SW(((k2 &1)<<12) + d8r4(k2 >>1))];
            v2 zd = buf[SW(((k2c&1)<<12) + d8r4(k2c>>1))];
            v2 U1 = 0.5f*(za + vconj(zb));
            v2 K1 = -0.5f*vrot(za - vconj(zb));
            v2 Yr = vcmul(U1, K1);                               // Y[r]
            v2 U2 = 0.5f*(zc + vconj(zd));
            v2 K2 = -0.5f*vrot(zc - vconj(zd));
            v2 Ys = vcmul(U2, K2);                               // Y[r+4096]
            v[i] = (Yr + Ys) + vrot(vcmul(cur, Yr - Ys));        // A + i*W^r*(Yr-Ys)
            cur = vcmul(cur, C16p);
        }
        __syncthreads();                         // all gathers done before butterfly writes
        v2 y[8];
        dft8_inv(v, y);
        int tb8 = 8*rev3(tid);
        #pragma unroll
        for (int m = 0; m < 8; ++m) buf[SW(tb8 + m)] = y[m];
    }
    __syncthreads();

    // ---- P6: ifft4096 middle passes ----
    r8_dit_inv<8 >(buf, tid);
    r8_dit_inv<64>(buf, tid);

    // ---- P7: fused P6-Q512 butterfly + epilogue. Only m<4 (n<2048 v2-pairs =
    //      first 4096 reals) survive the causal-conv truncation. ----
    {
        v2 t[8];
        #pragma unroll
        for (int k = 0; k < 8; ++k) t[k] = buf[SW(tid + 512*k)];
        apply_tw_inv(t, 6.2831853072f / 4096.0f, tid);
        v2 y[8];
        dft8_inv(t, y);
        const float Dh = Din[h];
        const float sc = 1.0f / 8192.0f;
        const v2* u2 = (const v2*)(u + h*4096);
        v2*     out2 = (v2*)(out + h*4096);
        #pragma unroll
        for (int m = 0; m < 4; ++m) {
            int n = tid + 512*m;                 // v2-pair index -> outputs 2n, 2n+1
            out2[n] = sc*y[m] + Dh*u2[n];
        }
    }
}

extern "C" void kernel_launch(void* const* d_in, const int* in_sizes, int n_in,
                              void* d_out, int out_size, void* d_ws, size_t ws_size,
                              hipStream_t stream)
{
    const float* u       = (const float*)d_in[0];
    const float* Lre     = (const float*)d_in[1];
    const float* Lim     = (const float*)d_in[2];
    const float* Pre     = (const float*)d_in[3];
    const float* Pim     = (const float*)d_in[4];
    const float* Bre     = (const float*)d_in[5];
    const float* Bim     = (const float*)d_in[6];
    const float* Cin     = (const float*)d_in[7];
    const float* Din     = (const float*)d_in[8];
    const float* logstep = (const float*)d_in[9];
    float* out = (float*)d_out;
    const int H = in_sizes[8];  // D is [H,1]
    hipLaunchKernelGGL(s4_fused, dim3(H), dim3(NT), 0, stream,
                       u, Lre, Lim, Pre, Pim, Bre, Bim, Cin, Din, logstep, out);
}